// Round 4
// baseline (305.119 us; speedup 1.0000x reference)
//
#include <hip/hip_runtime.h>
#include <math.h>

#define T_TOKENS 4096
#define HIDDEN   2048
#define N_EXPERTS 8
#define N_ROWS   (N_EXPERTS * T_TOKENS)   // 32768 rows of router_indices
#define ROW_F4   (HIDDEN / 4)             // 512 float4 per row

// R6: DE-fused. R0-R3 showed a hard plateau at kernels ~110 us across three
// structures (serial-LDS, fused-XCD0, fused-balanced), while rocclr's pure
// fill does 6.4 TB/s with VGPR=8 / 10% occupancy. Theory: the fill is only
// fast when it is a PURE write stream; mixing router h-loads (HBM), W
// re-reads (L1/L2) and shuffle-reduces into the same waves/CUs throttles
// store issue + adds R/W turnaround. So: (1) clean router kernel, no LDS,
// 4 tokens/wave, 1 block/CU (target ~12 us); (2) clean fill kernel, pure
// stores (target ~48 us = 268 MB at rocclr's demonstrated rate).

// ---------------------------------------------------------------------------
// Router: 256 blocks x 256 (1 block/CU, bids round-robin XCDs). Wave w of
// block b computes tokens (b*4+w)*4 .. +3. Per k-step: 4 h float4 loads
// (streaming) + 8 W float4 loads (64 KB total, L1/L2-hot, shared by all
// waves in lockstep) + 32 float4 FMAs. W traffic per token = 16 KB.
// ---------------------------------------------------------------------------
__global__ __launch_bounds__(256) void router_kernel(
    const float* __restrict__ h, const float* __restrict__ w,
    float* __restrict__ out0, float* __restrict__ out2)
{
    const int wave = threadIdx.x >> 6;
    const int lane = threadIdx.x & 63;
    const int t0   = (blockIdx.x * 4 + wave) * 4;   // 256*4*4 = 4096 tokens

    const float4* h4 = (const float4*)h;
    const float4* w4 = (const float4*)w;

    float acc[4][N_EXPERTS];
    #pragma unroll
    for (int t = 0; t < 4; t++)
        #pragma unroll
        for (int e = 0; e < N_EXPERTS; e++) acc[t][e] = 0.f;

    #pragma unroll
    for (int k = 0; k < 8; k++) {
        float4 hv[4];
        #pragma unroll
        for (int t = 0; t < 4; t++)
            hv[t] = h4[(size_t)(t0 + t) * ROW_F4 + k * 64 + lane];
        #pragma unroll
        for (int e = 0; e < N_EXPERTS; e++) {
            float4 wv = w4[e * ROW_F4 + k * 64 + lane];
            #pragma unroll
            for (int t = 0; t < 4; t++)
                acc[t][e] += hv[t].x * wv.x + hv[t].y * wv.y
                           + hv[t].z * wv.z + hv[t].w * wv.w;
        }
    }

    // 64-lane shuffle reduction for all 32 accumulators
    #pragma unroll
    for (int t = 0; t < 4; t++)
        #pragma unroll
        for (int e = 0; e < N_EXPERTS; e++)
            #pragma unroll
            for (int off = 32; off > 0; off >>= 1)
                acc[t][e] += __shfl_down(acc[t][e], off, 64);

    if (lane == 0) {
        #pragma unroll
        for (int t = 0; t < 4; t++) {
            const int tok = t0 + t;
            // top-2 of 8; strict > keeps first index on ties (== lax.top_k)
            int i1 = 0; float v1 = acc[t][0];
            #pragma unroll
            for (int e = 1; e < N_EXPERTS; e++)
                if (acc[t][e] > v1) { v1 = acc[t][e]; i1 = e; }
            int i2 = -1; float v2 = -INFINITY;
            #pragma unroll
            for (int e = 0; e < N_EXPERTS; e++)
                if (e != i1 && acc[t][e] > v2) { v2 = acc[t][e]; i2 = e; }

            float s1 = 1.f / (1.f + expf(-v1));
            float s2 = 1.f / (1.f + expf(-v2));

            #pragma unroll
            for (int e = 0; e < N_EXPERTS; e++) {
                float val = (e == i1) ? s1 : ((e == i2) ? s2 : 0.f);
                out0[e * T_TOKENS + tok] = val;
                out2[e * T_TOKENS + tok] = val;
            }
        }
    }
}

// ---------------------------------------------------------------------------
// Fill: PURE write stream, nothing else in the kernel. 2048 blocks x 256
// (tiny VGPR -> 8 blocks/CU). Wave gw fills rows 4gw..4gw+3: per row one
// cvt + 8 wave-wide 1 KB dwordx4 stores, full-line, aligned, contiguous
// 32 KB per wave. Plain stores (nt bypassed L2 WC and was 6x slower, R2).
// ---------------------------------------------------------------------------
__global__ __launch_bounds__(256) void fill_kernel(float* __restrict__ out1)
{
    const int wave = threadIdx.x >> 6;
    const int lane = threadIdx.x & 63;
    const int gw   = blockIdx.x * 4 + wave;   // 0..8191
    const int r0   = gw * 4;

    float4* o4 = (float4*)out1;
    #pragma unroll
    for (int i = 0; i < 4; i++) {
        float v = (float)((r0 + i) & (T_TOKENS - 1));
        float4 vv = make_float4(v, v, v, v);
        float4* rowp = o4 + (size_t)(r0 + i) * ROW_F4;
        #pragma unroll
        for (int j = 0; j < 8; j++)
            rowp[j * 64 + lane] = vv;
    }
}

extern "C" void kernel_launch(void* const* d_in, const int* in_sizes, int n_in,
                              void* d_out, int out_size, void* d_ws, size_t ws_size,
                              hipStream_t stream) {
    const float* h = (const float*)d_in[0];   // [4096, 2048] f32
    const float* w = (const float*)d_in[1];   // [8, 2048] f32
    // d_in[2] = top_k (always 2 for this problem)

    float* out  = (float*)d_out;
    float* out0 = out;                                            // router_scores [8,4096]
    float* out1 = out + N_EXPERTS * T_TOKENS;                     // router_indices [32768,2048]
    float* out2 = out1 + (size_t)N_EXPERTS * T_TOKENS * HIDDEN;   // router_probs [32768,1]

    hipLaunchKernelGGL(router_kernel, dim3(256), dim3(256), 0, stream,
                       h, w, out0, out2);
    hipLaunchKernelGGL(fill_kernel, dim3(2048), dim3(256), 0, stream, out1);
}